// Round 2
// baseline (433.019 us; speedup 1.0000x reference)
//
#include <hip/hip_runtime.h>

// ---------------------------------------------------------------------------
// CAPA_62886911148616: windowed local attention, SC=11, c=64, b=2, 256x256.
// Correctness-first round: no global_load_lds, no bias buffer, syncthreads
// around the P LDS round-trip, K/V stored only for the 24x24 in-image tiles.
//
// MFMA f32_16x16x32_bf16 layouts used throughout:
//   A: m=lane&15, k=8*(lane>>4)+j   B: n=lane&15, k=8*(lane>>4)+j
//   C/D: col=lane&15, row=4*(lane>>4)+reg
// ---------------------------------------------------------------------------

typedef unsigned short ushort_t;
typedef unsigned int   uint32;
typedef __attribute__((ext_vector_type(8))) short short8;   // 8 x bf16 bits
typedef __attribute__((ext_vector_type(4))) float f32x4;

#define MFMA16(a,b,c) __builtin_amdgcn_mfma_f32_16x16x32_bf16(a,b,c,0,0,0)

#if __has_builtin(__builtin_amdgcn_exp2f)
#define EXP2(x) __builtin_amdgcn_exp2f(x)
#else
#define EXP2(x) exp2f(x)
#endif
#if __has_builtin(__builtin_amdgcn_rcpf)
#define RCP(x) __builtin_amdgcn_rcpf(x)
#else
#define RCP(x) (1.0f/(x))
#endif

// ws layout (bytes): Q | K | V  (each 2*576 tiles * 16KB) = 54 MiB total
#define QPKT_OFF   0u
#define KPKT_OFF   18874368u
#define VPKT_OFF   37748736u

__device__ __forceinline__ ushort_t f2bf(float f){
  uint32 u = __float_as_uint(f);
  u = (u + 0x7FFFu + ((u >> 16) & 1u)) >> 16;   // RNE
  return (ushort_t)u;
}

// ---------------------------------------------------------------------------
// Kernel 1: projections into MFMA-fragment "packet" tensors (bf16).
// K/Q packet: row16 = nt*2 + ks (nt = 16-pixel group, ks = 32-ch half);
//   within row: lane' = (pix&15) + 16*g, bytes encode ch within half.
// V packet: row16 = ntp*4 + t (t = 16-ch tile); lane = ch-sub + 16*keyquad;
//   uint32 pairs pack (key, key+16).
// ---------------------------------------------------------------------------

__device__ __forceinline__ short8 ldWfrag(const float* __restrict__ W, int t, int ks, int l15, int h){
  const float* p = W + (16*t + l15)*64 + 32*ks + 8*h;
  float4 a = *(const float4*)p;
  float4 b = *(const float4*)(p + 4);
  union { short8 v; ushort_t u[8]; } x;
  x.u[0]=f2bf(a.x); x.u[1]=f2bf(a.y); x.u[2]=f2bf(a.z); x.u[3]=f2bf(a.w);
  x.u[4]=f2bf(b.x); x.u[5]=f2bf(b.y); x.u[6]=f2bf(b.z); x.u[7]=f2bf(b.w);
  return x.v;
}

// gather 16 pixels (group nt) x 64 ch from planar [64][256][256] fp32 -> bf16
__device__ __forceinline__ void gatherX(const float* __restrict__ xs, int oy, int ox,
                                        int nt, int l15, int h, short8 xf[2]){
  int key = 16*nt + l15;
  int kyl = (key*745) >> 13;          // key/11 exact for key<128
  int kxl = key - kyl*11;
  int gy = oy + kyl, gx = ox + kxl;
  bool val = (key < 121) && ((unsigned)gy < 256u) && ((unsigned)gx < 256u);
  int off = val ? (gy*256 + gx) : 0;
  #pragma unroll
  for (int ks = 0; ks < 2; ++ks){
    union { short8 v; ushort_t u[8]; } x;
    #pragma unroll
    for (int j = 0; j < 8; ++j){
      float v = xs[(size_t)(32*ks + 8*h + j)*65536 + off];
      x.u[j] = val ? f2bf(v) : (ushort_t)0;
    }
    xf[ks] = x.v;
  }
}

// store one D[ch][pix] C-frag into K/Q packet layout (8 bytes)
__device__ __forceinline__ void storeK8(ushort_t* __restrict__ base, int nt, int t,
                                        int l15, int h, f32x4 a){
  uint32 lo = (uint32)f2bf(a[0]) | ((uint32)f2bf(a[1]) << 16);
  uint32 hi = (uint32)f2bf(a[2]) | ((uint32)f2bf(a[3]) << 16);
  int lanep = l15 + 16*((2*t + (h>>1)) & 3);
  size_t off = (size_t)((nt*2 + (t>>1))*64 + lanep)*16 + 8*(h&1);
  *(uint2*)((char*)base + off) = make_uint2(lo, hi);
}

__global__ __launch_bounds__(64) void proj_kernel(
    const float* __restrict__ xk, const float* __restrict__ xr,
    const float* __restrict__ Wq, const float* __restrict__ Wk, const float* __restrict__ Wv,
    ushort_t* __restrict__ qpkt, ushort_t* __restrict__ kpkt, ushort_t* __restrict__ vpkt)
{
  const int lane = threadIdx.x;
  const int l15 = lane & 15, h = lane >> 4;
  int bid = blockIdx.x;
  const f32x4 zero = {0.f, 0.f, 0.f, 0.f};

  if (bid < 1152){
    // --- K/V tile: image-aligned 11x11 tile (ty,tx) in [0,24)^2 ---
    const int b = bid / 576, rem = bid % 576, ty = rem / 24, tx = rem % 24;
    short8 wkf[4][2], wvf[4][2];
    #pragma unroll
    for (int t = 0; t < 4; ++t){
      wkf[t][0] = ldWfrag(Wk, t, 0, l15, h);  wkf[t][1] = ldWfrag(Wk, t, 1, l15, h);
      wvf[t][0] = ldWfrag(Wv, t, 0, l15, h);  wvf[t][1] = ldWfrag(Wv, t, 1, l15, h);
    }
    const float* xs = xr + (size_t)b*64*65536;
    ushort_t* kb = kpkt + (size_t)bid*8192;
    ushort_t* vb = vpkt + (size_t)bid*8192;
    const int oy = ty*11, ox = tx*11;
    #pragma unroll
    for (int ntp = 0; ntp < 4; ++ntp){
      short8 xf0[2], xf1[2];
      gatherX(xs, oy, ox, 2*ntp,   l15, h, xf0);
      gatherX(xs, oy, ox, 2*ntp+1, l15, h, xf1);
      #pragma unroll
      for (int t = 0; t < 4; ++t){
        // K: D[ch][pix] = Wk * X^T
        f32x4 ak0 = MFMA16(wkf[t][0], xf0[0], zero); ak0 = MFMA16(wkf[t][1], xf0[1], ak0);
        f32x4 ak1 = MFMA16(wkf[t][0], xf1[0], zero); ak1 = MFMA16(wkf[t][1], xf1[1], ak1);
        // V: D[pix][ch] = X * Wv^T
        f32x4 av0 = MFMA16(xf0[0], wvf[t][0], zero); av0 = MFMA16(xf0[1], wvf[t][1], av0);
        f32x4 av1 = MFMA16(xf1[0], wvf[t][0], zero); av1 = MFMA16(xf1[1], wvf[t][1], av1);
        storeK8(kb, 2*ntp,   t, l15, h, ak0);
        storeK8(kb, 2*ntp+1, t, l15, h, ak1);
        #pragma unroll
        for (int r = 0; r < 4; ++r){
          uint32 pk = (uint32)f2bf(av0[r]) | ((uint32)f2bf(av1[r]) << 16);
          *(uint32*)((char*)vb + (size_t)((ntp*4 + t)*64 + lane)*16 + 4*r) = pk;
        }
      }
    }
  } else {
    // --- Q window: 11x11 tile (wy,wx) of the 24x24 window grid ---
    bid -= 1152;
    const int b = bid / 576, rem = bid % 576, wy = rem / 24, wx = rem % 24;
    short8 wqf[4][2];
    #pragma unroll
    for (int t = 0; t < 4; ++t){
      wqf[t][0] = ldWfrag(Wq, t, 0, l15, h);  wqf[t][1] = ldWfrag(Wq, t, 1, l15, h);
    }
    const float* xs = xk + (size_t)b*64*65536;
    ushort_t* qb = qpkt + (size_t)bid*8192;
    const int oy = wy*11, ox = wx*11;
    #pragma unroll
    for (int nt = 0; nt < 8; ++nt){
      short8 xf[2];
      gatherX(xs, oy, ox, nt, l15, h, xf);
      #pragma unroll
      for (int t = 0; t < 4; ++t){
        f32x4 aq = MFMA16(wqf[t][0], xf[0], zero); aq = MFMA16(wqf[t][1], xf[1], aq);
        storeK8(qb, nt, t, l15, h, aq);
      }
    }
  }
}

// ---------------------------------------------------------------------------
// Kernel 2: per-window attention. 128 threads = 2 waves; wave = 64 query rows.
// LDS: K 16K | V 16K | P 2x4K = 40960 B
// ---------------------------------------------------------------------------
__global__ __launch_bounds__(128) void attn_kernel(
    const ushort_t* __restrict__ qpkt, const ushort_t* __restrict__ kpkt,
    const ushort_t* __restrict__ vpkt,
    const float* __restrict__ xref, const float* __restrict__ gamma,
    float* __restrict__ out)
{
  __shared__ __align__(16) char smem[40960];
  const int tid  = threadIdx.x;
  const int lane = tid & 63, wave = tid >> 6;
  const int bid  = blockIdx.x;
  const int b = bid / 576, wid = bid % 576, wy = wid / 24, wx = wid % 24;
  const int l15 = lane & 15, lQ = lane >> 4;
  const float C1 = 0.18033688011112042f;   // (1/sqrt(64)) / ln(2)

  // resident Q A-frags: wave handles query rows [64*wave, 64*wave+64)
  short8 qf[4][2];
  const ushort_t* qblk = qpkt + (size_t)bid*8192;
  #pragma unroll
  for (int mt = 0; mt < 4; ++mt)
    #pragma unroll
    for (int ks = 0; ks < 2; ++ks)
      qf[mt][ks] = *(const short8*)(qblk + (size_t)(((4*wave + mt)*2 + ks)*64 + lane)*8);

  f32x4 o[4][4];
  float lsum[4][4];
  #pragma unroll
  for (int mt = 0; mt < 4; ++mt){
    #pragma unroll
    for (int u = 0; u < 4; ++u) o[mt][u] = (f32x4){0.f,0.f,0.f,0.f};
    #pragma unroll
    for (int r = 0; r < 4; ++r) lsum[mt][r] = 0.f;
  }

  const uint32 pwbase = 32768u + (uint32)wave*4096u + (uint32)(4*lQ)*16u
                      + (uint32)((lane>>2)&3)*256u + (uint32)(lane&3)*4u;

  for (int ck = 0; ck < 9; ++ck){
    const int ty = wy - 1 + ck/3, tx = wx - 1 + ck%3;
    if ((unsigned)ty >= 24u || (unsigned)tx >= 24u) continue;  // fully masked tile
    const int blk = b*576 + ty*24 + tx;
    // --- stage K (wave0) and V (wave1) via registers ---
    {
      const float4* kg = (const float4*)(kpkt + (size_t)blk*8192);
      const float4* vg = (const float4*)(vpkt + (size_t)blk*8192);
      float4* sk = (float4*)smem;
      float4* sv = (float4*)(smem + 16384);
      if (wave == 0){
        #pragma unroll
        for (int i = 0; i < 16; ++i) sk[i*64 + lane] = kg[i*64 + lane];
      } else {
        #pragma unroll
        for (int i = 0; i < 16; ++i) sv[i*64 + lane] = vg[i*64 + lane];
      }
    }
    __syncthreads();

    const bool full = (ty < 23) && (tx < 23);   // interior tile: only key>=121 masked

    #pragma unroll
    for (int ntp = 0; ntp < 4; ++ntp){
      // key validity for this lane's two key columns
      const int key0 = 32*ntp + l15, key1 = key0 + 16;
      bool v0 = key0 < 121, v1 = key1 < 121;
      if (!full){
        int ky0 = (key0*745) >> 13, kx0 = key0 - ky0*11;
        int ky1 = (key1*745) >> 13, kx1 = key1 - ky1*11;
        v0 = v0 && (11*ty + ky0 < 256) && (11*tx + kx0 < 256);
        v1 = v1 && (11*ty + ky1 < 256) && (11*tx + kx1 < 256);
      }
      // ---- S phase: keys [32*ntp, 32*ntp+32) ----
      short8 kf00 = *(const short8*)(smem + ((4*ntp+0)*64 + lane)*16);
      short8 kf01 = *(const short8*)(smem + ((4*ntp+1)*64 + lane)*16);
      short8 kf10 = *(const short8*)(smem + ((4*ntp+2)*64 + lane)*16);
      short8 kf11 = *(const short8*)(smem + ((4*ntp+3)*64 + lane)*16);
      #pragma unroll
      for (int mt = 0; mt < 4; ++mt){
        f32x4 s0 = {0.f,0.f,0.f,0.f}, s1 = {0.f,0.f,0.f,0.f};
        s0 = MFMA16(qf[mt][0], kf00, s0); s0 = MFMA16(qf[mt][1], kf01, s0);
        s1 = MFMA16(qf[mt][0], kf10, s1); s1 = MFMA16(qf[mt][1], kf11, s1);
        #pragma unroll
        for (int r = 0; r < 4; ++r){
          float p0 = v0 ? EXP2(s0[r]*C1) : 0.f;    // no running max: |logit| small
          float p1 = v1 ? EXP2(s1[r]*C1) : 0.f;
          lsum[mt][r] += p0 + p1;
          uint32 pk = (uint32)f2bf(p0) | ((uint32)f2bf(p1) << 16);
          *(uint32*)(smem + pwbase + mt*1024 + r*16) = pk;
        }
      }
      __syncthreads();   // P visible before A-frag reads
      // ---- PV phase for this key group ----
      short8 vf0 = *(const short8*)(smem + 16384 + ((ntp*4+0)*64 + lane)*16);
      short8 vf1 = *(const short8*)(smem + 16384 + ((ntp*4+1)*64 + lane)*16);
      short8 vf2 = *(const short8*)(smem + 16384 + ((ntp*4+2)*64 + lane)*16);
      short8 vf3 = *(const short8*)(smem + 16384 + ((ntp*4+3)*64 + lane)*16);
      #pragma unroll
      for (int mt = 0; mt < 4; ++mt){
        short8 af = *(const short8*)(smem + 32768 + wave*4096 + (mt*64 + lane)*16);
        o[mt][0] = MFMA16(af, vf0, o[mt][0]);
        o[mt][1] = MFMA16(af, vf1, o[mt][1]);
        o[mt][2] = MFMA16(af, vf2, o[mt][2]);
        o[mt][3] = MFMA16(af, vf3, o[mt][3]);
      }
      __syncthreads();   // P/K/V reads complete before overwrite
    }
  }

  // ---- epilogue: reduce denominator across the 16 key-column lanes ----
  const float g = gamma[0];
  float wgt[4][4];
  #pragma unroll
  for (int mt = 0; mt < 4; ++mt)
    #pragma unroll
    for (int r = 0; r < 4; ++r){
      float v = lsum[mt][r];
      v += __shfl_xor(v, 1); v += __shfl_xor(v, 2);
      v += __shfl_xor(v, 4); v += __shfl_xor(v, 8);
      wgt[mt][r] = g * RCP(v);
    }

  #pragma unroll
  for (int mt = 0; mt < 4; ++mt){
    const int qbase = 16*(4*wave + mt) + 4*lQ;
    #pragma unroll
    for (int r = 0; r < 4; ++r){
      const int q = qbase + r;
      int qyl = (q*745) >> 13;
      int qxl = q - qyl*11;
      int y = wy*11 + qyl, x = wx*11 + qxl;
      if (q < 121 && y < 256 && x < 256){
        const int yx = y*256 + x;
        #pragma unroll
        for (int u = 0; u < 4; ++u){
          const int chn = 16*u + l15;
          size_t idx = (size_t)(b*64 + chn)*65536 + yx;
          out[idx] = xref[idx] + wgt[mt][r]*o[mt][u][r];
        }
      }
    }
  }
}

// ---------------------------------------------------------------------------
extern "C" void kernel_launch(void* const* d_in, const int* in_sizes, int n_in,
                              void* d_out, int out_size, void* d_ws, size_t ws_size,
                              hipStream_t stream)
{
  const float* xk = (const float*)d_in[0];
  const float* xr = (const float*)d_in[1];
  const float* Wq = (const float*)d_in[2];
  const float* Wk = (const float*)d_in[3];
  const float* Wv = (const float*)d_in[4];
  const float* gm = (const float*)d_in[5];
  float* out = (float*)d_out;
  char* ws = (char*)d_ws;
  ushort_t* qp = (ushort_t*)(ws + QPKT_OFF);
  ushort_t* kp = (ushort_t*)(ws + KPKT_OFF);
  ushort_t* vp = (ushort_t*)(ws + VPKT_OFF);
  (void)in_sizes; (void)n_in; (void)out_size; (void)ws_size;  // need 54 MiB ws

  proj_kernel<<<2304, 64, 0, stream>>>(xk, xr, Wq, Wk, Wv, qp, kp, vp);
  attn_kernel<<<1152, 128, 0, stream>>>(qp, kp, vp, xr, gm, out);
}

// Round 3
// 320.088 us; speedup vs baseline: 1.3528x; 1.3528x over previous
//
#include <hip/hip_runtime.h>

// ---------------------------------------------------------------------------
// CAPA_62886911148616: windowed local attention, SC=11, c=64, b=2, 256x256.
// R3: barrier-free attn (direct global fragment loads, wave-private P via LDS
// with XOR bank swizzle), coalesced rbuf epilogue, LDS-staged proj.
// MFMA f32_16x16x32_bf16: A m=lane&15,k=8h+j; B n=lane&15,k=8h+j;
// C/D col=lane&15,row=4h+reg.
// ---------------------------------------------------------------------------

typedef unsigned short ushort_t;
typedef unsigned int   uint32;
typedef __attribute__((ext_vector_type(8))) short short8;   // 8 x bf16 bits
typedef __attribute__((ext_vector_type(4))) float f32x4;

#define MFMA16(a,b,c) __builtin_amdgcn_mfma_f32_16x16x32_bf16(a,b,c,0,0,0)

#if __has_builtin(__builtin_amdgcn_exp2f)
#define EXP2(x) __builtin_amdgcn_exp2f(x)
#else
#define EXP2(x) exp2f(x)
#endif
#if __has_builtin(__builtin_amdgcn_rcpf)
#define RCP(x) __builtin_amdgcn_rcpf(x)
#else
#define RCP(x) (1.0f/(x))
#endif

// ws layout (bytes): Q | K | V packets, each 1152 tiles * 16KB = 56.6 MiB.
// rbuf (bf16 [win][q128][ch64] = 16KB/win) OVERLAYS qpkt (safe: each attn
// block reads exactly its own 8KB half before writing that same 8KB).
#define QPKT_OFF   0u
#define KPKT_OFF   18874368u
#define VPKT_OFF   37748736u

__device__ __forceinline__ ushort_t f2bf(float f){
  uint32 u = __float_as_uint(f);
  u = (u + 0x7FFFu + ((u >> 16) & 1u)) >> 16;   // RNE
  return (ushort_t)u;
}

// store one D[ch][pix] C-frag into K/Q packet layout (8 bytes, verified R2)
__device__ __forceinline__ void storeK8(ushort_t* __restrict__ base, int nt, int t,
                                        int l15, int h, f32x4 a){
  uint32 lo = (uint32)f2bf(a[0]) | ((uint32)f2bf(a[1]) << 16);
  uint32 hi = (uint32)f2bf(a[2]) | ((uint32)f2bf(a[3]) << 16);
  int lanep = l15 + 16*((2*t + (h>>1)) & 3);
  size_t off = (size_t)((nt*2 + (t>>1))*64 + lanep)*16 + 8*(h&1);
  *(uint2*)((char*)base + off) = make_uint2(lo, hi);
}

__device__ __forceinline__ short8 ldWfrag(const float* __restrict__ W, int t, int ks, int l15, int h){
  const float* p = W + (16*t + l15)*64 + 32*ks + 8*h;
  float4 a = *(const float4*)p;
  float4 b = *(const float4*)(p + 4);
  union { short8 v; ushort_t u[8]; } x;
  x.u[0]=f2bf(a.x); x.u[1]=f2bf(a.y); x.u[2]=f2bf(a.z); x.u[3]=f2bf(a.w);
  x.u[4]=f2bf(b.x); x.u[5]=f2bf(b.y); x.u[6]=f2bf(b.z); x.u[7]=f2bf(b.w);
  return x.v;
}

// ---------------------------------------------------------------------------
// Kernel 1: projections. 256 thr = 4 waves; LDS-staged X tile (coalesced).
// LDS X layout: [ch][px = y*11+x], row stride 129 words (h-groups offset by
// 8 banks -> 2-way-free frag reads); px in [121,128) zeroed (keeps V finite).
// ---------------------------------------------------------------------------
__global__ __launch_bounds__(256) void proj_kernel(
    const float* __restrict__ xk, const float* __restrict__ xr,
    const float* __restrict__ Wq, const float* __restrict__ Wk, const float* __restrict__ Wv,
    ushort_t* __restrict__ qpkt, ushort_t* __restrict__ kpkt, ushort_t* __restrict__ vpkt)
{
  __shared__ float sX[64*129 + 8];
  const int tid = threadIdx.x;
  const int lane = tid & 63, wv = tid >> 6;
  const int l15 = lane & 15, h = lane >> 4;
  const int bid = blockIdx.x;
  const bool isQ = bid >= 1152;
  const int id = isQ ? bid - 1152 : bid;
  const int b = id / 576, rem = id % 576, ty = rem / 24, tx = rem % 24;
  const float* xs = (isQ ? xk : xr) + (size_t)b*64*65536;
  const int oy = ty*11, ox = tx*11;

  { // stage: thread (ch = tid>>2, seg = tid&3): 11 float4 row loads
    const int ch = tid >> 2, seg = tid & 3;
    const int xa  = ox & ~3;
    const int xg0 = xa + 4*seg;
    const bool fastx = (xg0 + 3) <= 255;
    const int lx0 = xg0 - ox;
    #pragma unroll
    for (int y = 0; y < 11; ++y){
      const int gy = oy + y;
      const bool rowok = gy < 256;
      float v0e, v1e, v2e, v3e;
      if (rowok && fastx){
        float4 v = *(const float4*)(xs + (size_t)ch*65536 + gy*256 + xg0);
        v0e = v.x; v1e = v.y; v2e = v.z; v3e = v.w;
      } else {
        v0e = (rowok && (xg0+0) < 256) ? xs[(size_t)ch*65536 + gy*256 + xg0+0] : 0.f;
        v1e = (rowok && (xg0+1) < 256) ? xs[(size_t)ch*65536 + gy*256 + xg0+1] : 0.f;
        v2e = (rowok && (xg0+2) < 256) ? xs[(size_t)ch*65536 + gy*256 + xg0+2] : 0.f;
        v3e = (rowok && (xg0+3) < 256) ? xs[(size_t)ch*65536 + gy*256 + xg0+3] : 0.f;
      }
      if (lx0+0 >= 0 && lx0+0 < 11) sX[ch*129 + y*11 + lx0+0] = v0e;
      if (lx0+1 >= 0 && lx0+1 < 11) sX[ch*129 + y*11 + lx0+1] = v1e;
      if (lx0+2 >= 0 && lx0+2 < 11) sX[ch*129 + y*11 + lx0+2] = v2e;
      if (lx0+3 >= 0 && lx0+3 < 11) sX[ch*129 + y*11 + lx0+3] = v3e;
    }
    if (tid < 64){
      #pragma unroll
      for (int pz = 121; pz < 128; ++pz) sX[tid*129 + pz] = 0.f;
    }
  }
  __syncthreads();

  const f32x4 zero = {0.f, 0.f, 0.f, 0.f};
  // frag builder from LDS (same semantics as R2's gatherX)
  #define XFL(nt, ks, dst) { \
    const int px_ = 16*(nt) + l15; \
    union { short8 v; ushort_t u[8]; } r_; \
    _Pragma("unroll") \
    for (int j_ = 0; j_ < 8; ++j_){ \
      int ch_ = 32*(ks) + 8*h + j_; \
      r_.u[j_] = f2bf(sX[ch_*129 + px_]); \
    } \
    dst = r_.v; }

  if (!isQ){
    short8 wkf[4][2], wvf[4][2];
    #pragma unroll
    for (int t = 0; t < 4; ++t){
      wkf[t][0] = ldWfrag(Wk, t, 0, l15, h);  wkf[t][1] = ldWfrag(Wk, t, 1, l15, h);
      wvf[t][0] = ldWfrag(Wv, t, 0, l15, h);  wvf[t][1] = ldWfrag(Wv, t, 1, l15, h);
    }
    ushort_t* kb = kpkt + (size_t)id*8192;
    ushort_t* vb = vpkt + (size_t)id*8192;
    const int nt0 = 2*wv, nt1 = 2*wv + 1;
    short8 xf0[2], xf1[2];
    XFL(nt0, 0, xf0[0]); XFL(nt0, 1, xf0[1]);
    XFL(nt1, 0, xf1[0]); XFL(nt1, 1, xf1[1]);
    #pragma unroll
    for (int t = 0; t < 4; ++t){
      f32x4 ak0 = MFMA16(wkf[t][0], xf0[0], zero); ak0 = MFMA16(wkf[t][1], xf0[1], ak0);
      f32x4 ak1 = MFMA16(wkf[t][0], xf1[0], zero); ak1 = MFMA16(wkf[t][1], xf1[1], ak1);
      f32x4 av0 = MFMA16(xf0[0], wvf[t][0], zero); av0 = MFMA16(xf0[1], wvf[t][1], av0);
      f32x4 av1 = MFMA16(xf1[0], wvf[t][0], zero); av1 = MFMA16(xf1[1], wvf[t][1], av1);
      storeK8(kb, nt0, t, l15, h, ak0);
      storeK8(kb, nt1, t, l15, h, ak1);
      uint4 pv;
      pv.x = (uint32)f2bf(av0[0]) | ((uint32)f2bf(av1[0]) << 16);
      pv.y = (uint32)f2bf(av0[1]) | ((uint32)f2bf(av1[1]) << 16);
      pv.z = (uint32)f2bf(av0[2]) | ((uint32)f2bf(av1[2]) << 16);
      pv.w = (uint32)f2bf(av0[3]) | ((uint32)f2bf(av1[3]) << 16);
      *(uint4*)((char*)vb + (size_t)((wv*4 + t)*64 + lane)*16) = pv;
    }
  } else {
    short8 wqf[4][2];
    #pragma unroll
    for (int t = 0; t < 4; ++t){
      wqf[t][0] = ldWfrag(Wq, t, 0, l15, h);  wqf[t][1] = ldWfrag(Wq, t, 1, l15, h);
    }
    ushort_t* qb = qpkt + (size_t)id*8192;
    #pragma unroll
    for (int nn = 0; nn < 2; ++nn){
      const int nt = 2*wv + nn;
      short8 xf[2];
      XFL(nt, 0, xf[0]); XFL(nt, 1, xf[1]);
      #pragma unroll
      for (int t = 0; t < 4; ++t){
        f32x4 aq = MFMA16(wqf[t][0], xf[0], zero); aq = MFMA16(wqf[t][1], xf[1], aq);
        storeK8(qb, nt, t, l15, h, aq);
      }
    }
  }
  #undef XFL
}

// ---------------------------------------------------------------------------
// Kernel 2: attention. 64-thread blocks (1 wave = 64 query rows of a window),
// ZERO block barriers. K/V frags loaded global->VGPR. P transpose via 4KB
// wave-private LDS with XOR swizzle. Writes normalized bf16 r into qpkt slot.
// ---------------------------------------------------------------------------
__global__ __launch_bounds__(64) void attn_kernel(
    ushort_t* qpkt,                      // aliases rbuf! no __restrict__
    const ushort_t* __restrict__ kpkt, const ushort_t* __restrict__ vpkt,
    const float* __restrict__ gamma)
{
  __shared__ __align__(16) char smem[4096];
  const int lane = threadIdx.x;
  const int g = (blockIdx.x & 7)*288 + (blockIdx.x >> 3);   // XCD-contiguous work
  const int win = g >> 1, wave = g & 1;
  const int b = win / 576, wid = win % 576, wy = wid / 24, wx = wid % 24;
  const int l15 = lane & 15, lQ = lane >> 4;
  const int q1 = lane & 3, q2 = (lane >> 2) & 3;
  const float C1 = 0.18033688011112042f;   // (1/8) / ln(2)

  short8 qf[4][2];
  {
    const ushort_t* qblk = qpkt + (size_t)win*8192;
    #pragma unroll
    for (int mt = 0; mt < 4; ++mt){
      qf[mt][0] = *(const short8*)(qblk + (size_t)(((4*wave+mt)*2 + 0)*64 + lane)*8);
      qf[mt][1] = *(const short8*)(qblk + (size_t)(((4*wave+mt)*2 + 1)*64 + lane)*8);
    }
  }

  f32x4 o[4][4];
  float lsum[4][4];
  #pragma unroll
  for (int mt = 0; mt < 4; ++mt){
    #pragma unroll
    for (int u = 0; u < 4; ++u) o[mt][u] = (f32x4){0.f,0.f,0.f,0.f};
    #pragma unroll
    for (int r = 0; r < 4; ++r) lsum[mt][r] = 0.f;
  }

  const int pbase = 64*lQ + 256*q2 + 4*q1;                 // bits4-5 free for r^q2
  const int aidx  = (lane ^ ((lane>>4)&3)) << 4;           // read-side XOR swizzle

  #pragma unroll 1
  for (int ck = 0; ck < 9; ++ck){
    const int ty = wy - 1 + ck/3, tx = wx - 1 + ck%3;
    if ((unsigned)ty >= 24u || (unsigned)tx >= 24u) continue;
    const int blk = b*576 + ty*24 + tx;
    const char* kg = (const char*)(kpkt + (size_t)blk*8192);
    const char* vg = (const char*)(vpkt + (size_t)blk*8192);
    const bool full = (ty < 23) && (tx < 23);

    #pragma unroll
    for (int ntp = 0; ntp < 4; ++ntp){
      const int key0 = 32*ntp + l15, key1 = key0 + 16;
      bool v0 = key0 < 121, v1 = key1 < 121;
      if (!full){
        int ky0 = (key0*745) >> 13, kx0 = key0 - ky0*11;
        int ky1 = (key1*745) >> 13, kx1 = key1 - ky1*11;
        v0 = v0 && (11*ty + ky0 < 256) && (11*tx + kx0 < 256);
        v1 = v1 && (11*ty + ky1 < 256) && (11*tx + kx1 < 256);
      }
      short8 kf00 = *(const short8*)(kg + ((4*ntp+0)*64 + lane)*16);
      short8 kf01 = *(const short8*)(kg + ((4*ntp+1)*64 + lane)*16);
      short8 kf10 = *(const short8*)(kg + ((4*ntp+2)*64 + lane)*16);
      short8 kf11 = *(const short8*)(kg + ((4*ntp+3)*64 + lane)*16);
      #pragma unroll
      for (int mt = 0; mt < 4; ++mt){
        f32x4 s0 = {0.f,0.f,0.f,0.f}, s1 = {0.f,0.f,0.f,0.f};
        s0 = MFMA16(qf[mt][0], kf00, s0); s0 = MFMA16(qf[mt][1], kf01, s0);
        s1 = MFMA16(qf[mt][0], kf10, s1); s1 = MFMA16(qf[mt][1], kf11, s1);
        #pragma unroll
        for (int r = 0; r < 4; ++r){
          float p0 = v0 ? EXP2(s0[r]*C1) : 0.f;    // no running max: |logit| small
          float p1 = v1 ? EXP2(s1[r]*C1) : 0.f;
          lsum[mt][r] += p0 + p1;
          uint32 pk = (uint32)f2bf(p0) | ((uint32)f2bf(p1) << 16);
          *(uint32*)(smem + pbase + mt*1024 + ((r ^ q2) << 4)) = pk;
        }
      }
      __asm__ volatile("s_waitcnt lgkmcnt(0)" ::: "memory");  // DS in-order; drain P writes
      short8 vf0 = *(const short8*)(vg + ((ntp*4+0)*64 + lane)*16);
      short8 vf1 = *(const short8*)(vg + ((ntp*4+1)*64 + lane)*16);
      short8 vf2 = *(const short8*)(vg + ((ntp*4+2)*64 + lane)*16);
      short8 vf3 = *(const short8*)(vg + ((ntp*4+3)*64 + lane)*16);
      #pragma unroll
      for (int mt = 0; mt < 4; ++mt){
        short8 af = *(const short8*)(smem + mt*1024 + aidx);
        o[mt][0] = MFMA16(af, vf0, o[mt][0]);
        o[mt][1] = MFMA16(af, vf1, o[mt][1]);
        o[mt][2] = MFMA16(af, vf2, o[mt][2]);
        o[mt][3] = MFMA16(af, vf3, o[mt][3]);
      }
      __asm__ volatile("" ::: "memory");   // pin next-iter P writes after af reads
    }
  }

  // epilogue: denominator reduce + normalized bf16 r into this block's own
  // 8KB half of qpkt[win] (all qf reads above precede these writes).
  const float gm = gamma[0];
  ushort_t* rb = qpkt + (size_t)win*8192;
  #pragma unroll
  for (int mt = 0; mt < 4; ++mt){
    #pragma unroll
    for (int r = 0; r < 4; ++r){
      float v = lsum[mt][r];
      v += __shfl_xor(v, 1); v += __shfl_xor(v, 2);
      v += __shfl_xor(v, 4); v += __shfl_xor(v, 8);
      const float wg = gm * RCP(v);
      const int q = 64*wave + 16*mt + 4*lQ + r;
      #pragma unroll
      for (int u = 0; u < 4; ++u){
        rb[(size_t)q*64 + 16*u + l15] = f2bf(wg * o[mt][u][r]);
      }
    }
  }
}

// ---------------------------------------------------------------------------
// Kernel 3: out = xref + r  (coalesced float4 writes; r gathered from L2/L3)
// ---------------------------------------------------------------------------
__global__ __launch_bounds__(256) void ep_kernel(
    const float* __restrict__ xref, const ushort_t* __restrict__ rbuf,
    float* __restrict__ out)
{
  const int t = blockIdx.x*256 + threadIdx.x;
  const int base = t*4;                          // [2][64][256][256] fp32
  const int b   = base >> 22;
  const int rem = base & 4194303;
  const int ch  = rem >> 16;
  const int yx  = rem & 65535;
  const int y = yx >> 8, x0 = yx & 255;
  const int wy = (y*745) >> 13, qy = y - wy*11;  // magic /11, exact for y<256
  float4 xr4 = *(const float4*)(xref + base);
  const ushort_t* rbb = rbuf + ((size_t)(b*576 + wy*24)*128)*64 + ch;
  float res[4];
  #pragma unroll
  for (int e = 0; e < 4; ++e){
    int x = x0 + e;
    int wxx = (x*745) >> 13, qx = x - wxx*11;
    size_t idx = ((size_t)wxx*128 + (qy*11 + qx))*64;
    uint32 uv = rbb[idx];
    float rv = __uint_as_float(uv << 16);
    res[e] = ((const float*)&xr4)[e] + rv;
  }
  *(float4*)(out + base) = make_float4(res[0], res[1], res[2], res[3]);
}

// ---------------------------------------------------------------------------
extern "C" void kernel_launch(void* const* d_in, const int* in_sizes, int n_in,
                              void* d_out, int out_size, void* d_ws, size_t ws_size,
                              hipStream_t stream)
{
  const float* xk = (const float*)d_in[0];
  const float* xr = (const float*)d_in[1];
  const float* Wq = (const float*)d_in[2];
  const float* Wk = (const float*)d_in[3];
  const float* Wv = (const float*)d_in[4];
  const float* gm = (const float*)d_in[5];
  float* out = (float*)d_out;
  char* ws = (char*)d_ws;
  ushort_t* qp = (ushort_t*)(ws + QPKT_OFF);   // rbuf overlays this region
  ushort_t* kp = (ushort_t*)(ws + KPKT_OFF);
  ushort_t* vp = (ushort_t*)(ws + VPKT_OFF);
  (void)in_sizes; (void)n_in; (void)out_size; (void)ws_size;  // needs 56.6 MiB (R2-proven)

  proj_kernel<<<2304, 256, 0, stream>>>(xk, xr, Wq, Wk, Wv, qp, kp, vp);
  attn_kernel<<<2304, 64, 0, stream>>>(qp, kp, vp, gm);
  ep_kernel<<<8192, 256, 0, stream>>>(xr, qp, out);
}

// Round 4
// 261.858 us; speedup vs baseline: 1.6536x; 1.2224x over previous
//
#include <hip/hip_runtime.h>

// ---------------------------------------------------------------------------
// CAPA_62886911148616: windowed local attention, SC=11, c=64, b=2, 256x256.
// R4: S^T-form attention -> P exits QK^T already in A-operand layout (V-packet
// key-permuted by pi). Zero LDS / zero fences in attn. cvt_pk_bf16 packs,
// Wq pre-scaled by 1/(8 ln2), slot-layout proj staging, LDS-tiled epilogue.
// MFMA f32_16x16x32_bf16: A m=lane&15,k=8h+j; B n=lane&15,k=8h+j;
// C/D col=lane&15 (=B's n), row=4h+reg (=A's m).
// ---------------------------------------------------------------------------

typedef unsigned short ushort_t;
typedef unsigned int   uint32;
typedef __attribute__((ext_vector_type(8))) short short8;   // 8 x bf16 bits
typedef __attribute__((ext_vector_type(4))) float f32x4;

#define MFMA16(a,b,c) __builtin_amdgcn_mfma_f32_16x16x32_bf16(a,b,c,0,0,0)

#if __has_builtin(__builtin_amdgcn_exp2f)
#define EXP2(x) __builtin_amdgcn_exp2f(x)
#else
#define EXP2(x) exp2f(x)
#endif
#if __has_builtin(__builtin_amdgcn_rcpf)
#define RCP(x) __builtin_amdgcn_rcpf(x)
#else
#define RCP(x) (1.0f/(x))
#endif

// ws layout (bytes): Q | K | V packets, each 1152 tiles * 16KB = 56.6 MiB.
// rbuf (bf16 [win][q128][ch64]) overlays qpkt (each attn block reads its own
// 8KB half fully before writing that same 8KB).
#define QPKT_OFF   0u
#define KPKT_OFF   18874368u
#define VPKT_OFF   37748736u

__device__ __forceinline__ ushort_t f2bf(float f){
  uint32 u = __float_as_uint(f);
  u = (u + 0x7FFFu + ((u >> 16) & 1u)) >> 16;   // RNE
  return (ushort_t)u;
}

// packed f32x2 -> bf16x2 (lo = a, hi = b); gfx950 has v_cvt_pk_bf16_f32
__device__ __forceinline__ uint32 pkbf(float a, float b){
#if __has_builtin(__builtin_amdgcn_cvt_pk_bf16_f32)
  typedef __attribute__((ext_vector_type(2))) __bf16 bf2;
  union { bf2 v; uint32 u; } c;
  c.v = __builtin_amdgcn_cvt_pk_bf16_f32(a, b);
  return c.u;
#else
  return (uint32)f2bf(a) | ((uint32)f2bf(b) << 16);
#endif
}

// store one D[ch][pix] C-frag into K/Q packet layout (8 bytes, R2-verified)
__device__ __forceinline__ void storeK8(ushort_t* __restrict__ base, int nt, int t,
                                        int l15, int h, f32x4 a){
  uint32 lo = pkbf(a[0], a[1]);
  uint32 hi = pkbf(a[2], a[3]);
  int lanep = l15 + 16*((2*t + (h>>1)) & 3);
  size_t off = (size_t)((nt*2 + (t>>1))*64 + lanep)*16 + 8*(h&1);
  *(uint2*)((char*)base + off) = make_uint2(lo, hi);
}

__device__ __forceinline__ short8 ldWfrag(const float* __restrict__ W, int t, int ks,
                                          int l15, int h, float scale){
  const float* p = W + (16*t + l15)*64 + 32*ks + 8*h;
  float4 a = *(const float4*)p;
  float4 b = *(const float4*)(p + 4);
  union { uint4 u; short8 s; } x;
  x.u.x = pkbf(a.x*scale, a.y*scale);
  x.u.y = pkbf(a.z*scale, a.w*scale);
  x.u.z = pkbf(b.x*scale, b.y*scale);
  x.u.w = pkbf(b.z*scale, b.w*scale);
  return x.s;
}

// ---------------------------------------------------------------------------
// Kernel 1: projections. 256 thr = 4 waves. LDS slot layout: [ch][y(12)][16],
// stride 192 words (16B-aligned rows; row 11 zeroed for px>=121). Global-
// aligned slots -> unconditional float4/ds_write_b128 staging (fast path).
// ---------------------------------------------------------------------------
__global__ __launch_bounds__(256) void proj_kernel(
    const float* __restrict__ xk, const float* __restrict__ xr,
    const float* __restrict__ Wq, const float* __restrict__ Wk, const float* __restrict__ Wv,
    ushort_t* __restrict__ qpkt, ushort_t* __restrict__ kpkt, ushort_t* __restrict__ vpkt)
{
  __shared__ __align__(16) float sX[64*192];
  const int tid = threadIdx.x;
  const int lane = tid & 63, wv = tid >> 6;
  const int l15 = lane & 15, h = lane >> 4;
  const int bid = blockIdx.x;
  const bool isQ = bid >= 1152;
  const int id = isQ ? bid - 1152 : bid;
  const int b = id / 576, rem = id % 576, ty = rem / 24, tx = rem % 24;
  const float* xs = (isQ ? xk : xr) + (size_t)b*64*65536;
  const int oy = ty*11, ox = tx*11;
  const int ox3 = ox & 3, xa = ox - ox3;

  // zero row 11 (px 121..127 read as 0)
  #pragma unroll
  for (int i = tid; i < 1024; i += 256) sX[(i>>4)*192 + 176 + (i&15)] = 0.f;

  { // stage 16-float x-span per (ch, seg)
    const int ch = tid >> 2, seg = tid & 3;
    const float* rowp = xs + (size_t)ch*65536 + (size_t)oy*256 + (xa + 4*seg);
    float* sdst = sX + ch*192 + 4*seg;
    if (ty < 23 && tx < 23){
      #pragma unroll
      for (int y = 0; y < 11; ++y)
        *(float4*)(sdst + y*16) = *(const float4*)(rowp + y*256);
    } else {
      const int xg = xa + 4*seg;
      #pragma unroll
      for (int y = 0; y < 11; ++y){
        const bool rk = (oy + y) < 256;
        float4 v;
        v.x = (rk && xg+0 < 256) ? rowp[y*256+0] : 0.f;
        v.y = (rk && xg+1 < 256) ? rowp[y*256+1] : 0.f;
        v.z = (rk && xg+2 < 256) ? rowp[y*256+2] : 0.f;
        v.w = (rk && xg+3 < 256) ? rowp[y*256+3] : 0.f;
        *(float4*)(sdst + y*16) = v;
      }
    }
  }
  __syncthreads();

  const f32x4 zero = {0.f, 0.f, 0.f, 0.f};
  // build bf16 X-frag from LDS slots (8 ch at stride 192 for px = 16nt+l15)
  #define XFL(nt, ks, dst) { \
    const int px_ = 16*(nt) + l15; \
    const int y_ = (px_*745) >> 13; \
    const float* pp_ = sX + (32*(ks) + 8*h)*192 + y_*16 + (px_ - y_*11) + ox3; \
    union { uint4 u; short8 s; } r_; \
    r_.u.x = pkbf(pp_[0],    pp_[192]); \
    r_.u.y = pkbf(pp_[384],  pp_[576]); \
    r_.u.z = pkbf(pp_[768],  pp_[960]); \
    r_.u.w = pkbf(pp_[1152], pp_[1344]); \
    dst = r_.s; }

  if (!isQ){
    short8 wkf[4][2], wvf[4][2];
    #pragma unroll
    for (int t = 0; t < 4; ++t){
      wkf[t][0] = ldWfrag(Wk, t, 0, l15, h, 1.f);  wkf[t][1] = ldWfrag(Wk, t, 1, l15, h, 1.f);
      wvf[t][0] = ldWfrag(Wv, t, 0, l15, h, 1.f);  wvf[t][1] = ldWfrag(Wv, t, 1, l15, h, 1.f);
    }
    ushort_t* kb = kpkt + (size_t)id*8192;
    ushort_t* vb = vpkt + (size_t)id*8192;
    const int nt0 = 2*wv, nt1 = 2*wv + 1;
    short8 xf0[2], xf1[2];
    XFL(nt0, 0, xf0[0]); XFL(nt0, 1, xf0[1]);
    XFL(nt1, 0, xf1[0]); XFL(nt1, 1, xf1[1]);
    #pragma unroll
    for (int t = 0; t < 4; ++t){
      f32x4 ak0 = MFMA16(wkf[t][0], xf0[0], zero); ak0 = MFMA16(wkf[t][1], xf0[1], ak0);
      f32x4 ak1 = MFMA16(wkf[t][0], xf1[0], zero); ak1 = MFMA16(wkf[t][1], xf1[1], ak1);
      f32x4 av0 = MFMA16(xf0[0], wvf[t][0], zero); av0 = MFMA16(xf0[1], wvf[t][1], av0);
      f32x4 av1 = MFMA16(xf1[0], wvf[t][0], zero); av1 = MFMA16(xf1[1], wvf[t][1], av1);
      storeK8(kb, nt0, t, l15, h, ak0);
      storeK8(kb, nt1, t, l15, h, ak1);
      // V packet, pi key order: slots {av0[0..3], av1[0..3]}
      uint4 pv;
      pv.x = pkbf(av0[0], av0[1]); pv.y = pkbf(av0[2], av0[3]);
      pv.z = pkbf(av1[0], av1[1]); pv.w = pkbf(av1[2], av1[3]);
      *(uint4*)((char*)vb + (size_t)((wv*4 + t)*64 + lane)*16) = pv;
    }
  } else {
    const float C1 = 0.18033688011112042f;   // (1/8) / ln(2), folded into Q
    short8 wqf[4][2];
    #pragma unroll
    for (int t = 0; t < 4; ++t){
      wqf[t][0] = ldWfrag(Wq, t, 0, l15, h, C1);  wqf[t][1] = ldWfrag(Wq, t, 1, l15, h, C1);
    }
    ushort_t* qb = qpkt + (size_t)id*8192;
    #pragma unroll
    for (int nn = 0; nn < 2; ++nn){
      const int nt = 2*wv + nn;
      short8 xf[2];
      XFL(nt, 0, xf[0]); XFL(nt, 1, xf[1]);
      #pragma unroll
      for (int t = 0; t < 4; ++t){
        f32x4 aq = MFMA16(wqf[t][0], xf[0], zero); aq = MFMA16(wqf[t][1], xf[1], aq);
        storeK8(qb, nt, t, l15, h, aq);
      }
    }
  }
  #undef XFL
}

// ---------------------------------------------------------------------------
// Kernel 2: attention, S^T form. 64-thr blocks, NO LDS, NO fences.
// S^T = MFMA(A=K, B=Q): row=key(4h+r), col=query(l15). exp2 -> P^T values are
// already the PV A-frag (m=query l15, k=8h+j -> key pi(8h+j)); V-packet is
// pi-ordered. O: row=query(4h+r), col=ch(l15) — same epilogue as R3.
// ---------------------------------------------------------------------------
__global__ __launch_bounds__(64) void attn_kernel(
    ushort_t* qpkt,                      // aliases rbuf! no __restrict__
    const ushort_t* __restrict__ kpkt, const ushort_t* __restrict__ vpkt,
    const float* __restrict__ gamma)
{
  const int lane = threadIdx.x;
  const int g = (blockIdx.x & 7)*288 + (blockIdx.x >> 3);   // XCD swizzle
  const int win = g >> 1, wave = g & 1;
  const int b = win / 576, wid = win % 576, wy = wid / 24, wx = wid % 24;
  const int l15 = lane & 15, h = lane >> 4;

  short8 qf[4][2];
  {
    const ushort_t* qblk = qpkt + (size_t)win*8192;
    #pragma unroll
    for (int mt = 0; mt < 4; ++mt){
      qf[mt][0] = *(const short8*)(qblk + (size_t)(((4*wave+mt)*2 + 0)*64 + lane)*8);
      qf[mt][1] = *(const short8*)(qblk + (size_t)(((4*wave+mt)*2 + 1)*64 + lane)*8);
    }
  }

  f32x4 o[4][4];
  float lsum[4] = {0.f, 0.f, 0.f, 0.f};
  #pragma unroll
  for (int mt = 0; mt < 4; ++mt)
    #pragma unroll
    for (int u = 0; u < 4; ++u) o[mt][u] = (f32x4){0.f,0.f,0.f,0.f};

  const f32x4 zz = {0.f,0.f,0.f,0.f};

  #pragma unroll 1
  for (int ck = 0; ck < 9; ++ck){
    const int ty = wy - 1 + ck/3, tx = wx - 1 + ck%3;
    if ((unsigned)ty >= 24u || (unsigned)tx >= 24u) continue;
    const size_t tbase = (size_t)(b*576 + ty*24 + tx)*8192;
    const char* kg = (const char*)(kpkt + tbase);
    const char* vg = (const char*)(vpkt + tbase);
    const bool ey = (ty == 23), ex = (tx == 23);

    #pragma unroll
    for (int ntp = 0; ntp < 4; ++ntp){
      short8 kf00 = *(const short8*)(kg + ((4*ntp+0)*64 + lane)*16);
      short8 kf01 = *(const short8*)(kg + ((4*ntp+1)*64 + lane)*16);
      short8 kf10 = *(const short8*)(kg + ((4*ntp+2)*64 + lane)*16);
      short8 kf11 = *(const short8*)(kg + ((4*ntp+3)*64 + lane)*16);
      short8 vf0  = *(const short8*)(vg + ((4*ntp+0)*64 + lane)*16);
      short8 vf1  = *(const short8*)(vg + ((4*ntp+1)*64 + lane)*16);
      short8 vf2  = *(const short8*)(vg + ((4*ntp+2)*64 + lane)*16);
      short8 vf3  = *(const short8*)(vg + ((4*ntp+3)*64 + lane)*16);

      // key validity for this lane's 8 keys (kt tile x reg r)
      bool okk[8];
      #pragma unroll
      for (int kt = 0; kt < 2; ++kt)
        #pragma unroll
        for (int r = 0; r < 4; ++r){
          const int kl = 32*ntp + 16*kt + 4*h + r;
          bool ok = kl < 121;
          if (ey | ex){
            const int ky = (kl*745) >> 13, kx = kl - ky*11;
            if (ey) ok = ok && (ky < 3);
            if (ex) ok = ok && (kx < 3);
          }
          okk[4*kt + r] = ok;
        }

      #pragma unroll
      for (int mt = 0; mt < 4; ++mt){
        f32x4 s0 = MFMA16(kf00, qf[mt][0], zz); s0 = MFMA16(kf01, qf[mt][1], s0);
        f32x4 s1 = MFMA16(kf10, qf[mt][0], zz); s1 = MFMA16(kf11, qf[mt][1], s1);
        float p[8];
        #pragma unroll
        for (int r = 0; r < 4; ++r){
          p[r]   = okk[r]   ? EXP2(s0[r]) : 0.f;   // Q pre-scaled; no running max
          p[4+r] = okk[4+r] ? EXP2(s1[r]) : 0.f;
        }
        lsum[mt] += ((p[0]+p[1]) + (p[2]+p[3])) + ((p[4]+p[5]) + (p[6]+p[7]));
        union { uint4 u; short8 s; } af;
        af.u.x = pkbf(p[0], p[1]); af.u.y = pkbf(p[2], p[3]);
        af.u.z = pkbf(p[4], p[5]); af.u.w = pkbf(p[6], p[7]);
        o[mt][0] = MFMA16(af.s, vf0, o[mt][0]);
        o[mt][1] = MFMA16(af.s, vf1, o[mt][1]);
        o[mt][2] = MFMA16(af.s, vf2, o[mt][2]);
        o[mt][3] = MFMA16(af.s, vf3, o[mt][3]);
      }
    }
  }

  // epilogue: lsum[mt] is per-lane partial for query (16mt + l15); reduce over
  // h-groups, fetch per-(h,r) denominator by shuffle, store normalized bf16 r.
  const float gm = gamma[0];
  ushort_t* rb = qpkt + (size_t)win*8192 + (size_t)wave*4096;
  #pragma unroll
  for (int mt = 0; mt < 4; ++mt){
    float v = lsum[mt];
    v += __shfl_xor(v, 16); v += __shfl_xor(v, 32);
    #pragma unroll
    for (int r = 0; r < 4; ++r){
      const float den = __shfl(v, 4*h + r);     // lane with l15' = 4h+r
      const float wg = gm * RCP(den);
      const int qs = 16*mt + 4*h + r;
      #pragma unroll
      for (int u = 0; u < 4; ++u)
        rb[(size_t)qs*64 + 16*u + l15] = f2bf(wg * o[mt][u][r]);
    }
  }
}

// ---------------------------------------------------------------------------
// Kernel 3: out = xref + r. LDS-tiled: rbuf gathered ch-major (coalesced),
// emitted x-major (coalesced). Block = (b, y, 64-px x-chunk).
// ---------------------------------------------------------------------------
__global__ __launch_bounds__(256) void ep_kernel(
    const float* __restrict__ xref, const ushort_t* __restrict__ rbuf,
    float* __restrict__ out)
{
  __shared__ float tile[64][65];
  const int tid = threadIdx.x;
  const int bidx = blockIdx.x;                 // 2048 = b(2) x y(256) x xc(4)
  const int xc = bidx & 3, y = (bidx >> 2) & 255, b = bidx >> 10;
  const int wy = (y*745) >> 13, qy = y - wy*11;
  { // phase A: gather (lanes = 64 consecutive ch -> 128B coalesced)
    const int ch = tid & 63, xs4 = tid >> 6;
    #pragma unroll
    for (int xi = 0; xi < 16; ++xi){
      const int xl = xi*4 + xs4;
      const int x = xc*64 + xl;
      const int wx = (x*745) >> 13, qx = x - wx*11;
      const size_t ridx = (size_t)(b*576 + wy*24 + wx)*8192 + (size_t)(qy*11 + qx)*64 + ch;
      tile[xl][ch] = __uint_as_float(((uint32)rbuf[ridx]) << 16);
    }
  }
  __syncthreads();
  { // phase B: add + store (lanes = 64 consecutive x -> 256B coalesced)
    const int xl = tid & 63, cg = tid >> 6;
    const size_t base = (size_t)b*4194304 + (size_t)y*256 + xc*64 + xl;
    #pragma unroll
    for (int ci = 0; ci < 16; ++ci){
      const int c2 = ci*4 + cg;
      const size_t idx = base + (size_t)c2*65536;
      out[idx] = xref[idx] + tile[xl][c2];
    }
  }
}

// ---------------------------------------------------------------------------
extern "C" void kernel_launch(void* const* d_in, const int* in_sizes, int n_in,
                              void* d_out, int out_size, void* d_ws, size_t ws_size,
                              hipStream_t stream)
{
  const float* xk = (const float*)d_in[0];
  const float* xr = (const float*)d_in[1];
  const float* Wq = (const float*)d_in[2];
  const float* Wk = (const float*)d_in[3];
  const float* Wv = (const float*)d_in[4];
  const float* gm = (const float*)d_in[5];
  float* out = (float*)d_out;
  char* ws = (char*)d_ws;
  ushort_t* qp = (ushort_t*)(ws + QPKT_OFF);   // rbuf overlays this region
  ushort_t* kp = (ushort_t*)(ws + KPKT_OFF);
  ushort_t* vp = (ushort_t*)(ws + VPKT_OFF);
  (void)in_sizes; (void)n_in; (void)out_size; (void)ws_size;  // needs 56.6 MiB

  proj_kernel<<<2304, 256, 0, stream>>>(xk, xr, Wq, Wk, Wv, qp, kp, vp);
  attn_kernel<<<2304, 64, 0, stream>>>(qp, kp, vp, gm);
  ep_kernel<<<2048, 256, 0, stream>>>(xr, qp, out);
}

// Round 5
// 251.069 us; speedup vs baseline: 1.7247x; 1.0430x over previous
//
#include <hip/hip_runtime.h>

// ---------------------------------------------------------------------------
// CAPA_62886911148616: windowed local attention, SC=11, c=64, b=2, 256x256.
// R5: attn rebuilt as 128-thr blocks (2 waves share one window's K/V) with a
// global_load_lds double-buffer pipeline: s_waitcnt vmcnt(8) + raw s_barrier
// keeps the next 16KB unit in flight during compute (AITER-style). Compute
// math identical to R4 (S^T form, pi-permuted V, zero P round-trip).
// MFMA f32_16x16x32_bf16: A m=lane&15,k=8h+j; B n=lane&15,k=8h+j;
// C/D col=lane&15, row=4h+reg.
// ---------------------------------------------------------------------------

typedef unsigned short ushort_t;
typedef unsigned int   uint32;
typedef unsigned long long uint64;
typedef __attribute__((ext_vector_type(8))) short short8;   // 8 x bf16 bits
typedef __attribute__((ext_vector_type(4))) float f32x4;

#define MFMA16(a,b,c) __builtin_amdgcn_mfma_f32_16x16x32_bf16(a,b,c,0,0,0)

#if __has_builtin(__builtin_amdgcn_exp2f)
#define EXP2(x) __builtin_amdgcn_exp2f(x)
#else
#define EXP2(x) exp2f(x)
#endif
#if __has_builtin(__builtin_amdgcn_rcpf)
#define RCP(x) __builtin_amdgcn_rcpf(x)
#else
#define RCP(x) (1.0f/(x))
#endif

// ws layout (bytes): Q | K | V packets, each 1152 tiles * 16KB = 56.6 MiB.
// rbuf (bf16 [win][q128][ch64]) overlays qpkt (each attn wave reads its own
// 4KB quarter fully before writing that same 4KB).
#define QPKT_OFF   0u
#define KPKT_OFF   18874368u
#define VPKT_OFF   37748736u

__device__ __forceinline__ ushort_t f2bf(float f){
  uint32 u = __float_as_uint(f);
  u = (u + 0x7FFFu + ((u >> 16) & 1u)) >> 16;   // RNE
  return (ushort_t)u;
}

// packed f32x2 -> bf16x2 (lo = a, hi = b); gfx950 has v_cvt_pk_bf16_f32
__device__ __forceinline__ uint32 pkbf(float a, float b){
#if __has_builtin(__builtin_amdgcn_cvt_pk_bf16_f32)
  typedef __attribute__((ext_vector_type(2))) __bf16 bf2;
  union { bf2 v; uint32 u; } c;
  c.v = __builtin_amdgcn_cvt_pk_bf16_f32(a, b);
  return c.u;
#else
  return (uint32)f2bf(a) | ((uint32)f2bf(b) << 16);
#endif
}

// store one D[ch][pix] C-frag into K/Q packet layout (8 bytes, R2-verified)
__device__ __forceinline__ void storeK8(ushort_t* __restrict__ base, int nt, int t,
                                        int l15, int h, f32x4 a){
  uint32 lo = pkbf(a[0], a[1]);
  uint32 hi = pkbf(a[2], a[3]);
  int lanep = l15 + 16*((2*t + (h>>1)) & 3);
  size_t off = (size_t)((nt*2 + (t>>1))*64 + lanep)*16 + 8*(h&1);
  *(uint2*)((char*)base + off) = make_uint2(lo, hi);
}

__device__ __forceinline__ short8 ldWfrag(const float* __restrict__ W, int t, int ks,
                                          int l15, int h, float scale){
  const float* p = W + (16*t + l15)*64 + 32*ks + 8*h;
  float4 a = *(const float4*)p;
  float4 b = *(const float4*)(p + 4);
  union { uint4 u; short8 s; } x;
  x.u.x = pkbf(a.x*scale, a.y*scale);
  x.u.y = pkbf(a.z*scale, a.w*scale);
  x.u.z = pkbf(b.x*scale, b.y*scale);
  x.u.w = pkbf(b.z*scale, b.w*scale);
  return x.s;
}

// ---------------------------------------------------------------------------
// Kernel 1: projections (R4-proven). 256 thr = 4 waves; LDS slot layout
// [ch][y(12)][16] fp32, stride 192 words; row 11 zeroed (px>=121 -> 0).
// ---------------------------------------------------------------------------
__global__ __launch_bounds__(256) void proj_kernel(
    const float* __restrict__ xk, const float* __restrict__ xr,
    const float* __restrict__ Wq, const float* __restrict__ Wk, const float* __restrict__ Wv,
    ushort_t* __restrict__ qpkt, ushort_t* __restrict__ kpkt, ushort_t* __restrict__ vpkt)
{
  __shared__ __align__(16) float sX[64*192];
  const int tid = threadIdx.x;
  const int lane = tid & 63, wv = tid >> 6;
  const int l15 = lane & 15, h = lane >> 4;
  const int bid = blockIdx.x;
  const bool isQ = bid >= 1152;
  const int id = isQ ? bid - 1152 : bid;
  const int b = id / 576, rem = id % 576, ty = rem / 24, tx = rem % 24;
  const float* xs = (isQ ? xk : xr) + (size_t)b*64*65536;
  const int oy = ty*11, ox = tx*11;
  const int ox3 = ox & 3, xa = ox - ox3;

  #pragma unroll
  for (int i = tid; i < 1024; i += 256) sX[(i>>4)*192 + 176 + (i&15)] = 0.f;

  { // stage 16-float x-span per (ch, seg)
    const int ch = tid >> 2, seg = tid & 3;
    const float* rowp = xs + (size_t)ch*65536 + (size_t)oy*256 + (xa + 4*seg);
    float* sdst = sX + ch*192 + 4*seg;
    if (ty < 23 && tx < 23){
      #pragma unroll
      for (int y = 0; y < 11; ++y)
        *(float4*)(sdst + y*16) = *(const float4*)(rowp + y*256);
    } else {
      const int xg = xa + 4*seg;
      #pragma unroll
      for (int y = 0; y < 11; ++y){
        const bool rk = (oy + y) < 256;
        float4 v;
        v.x = (rk && xg+0 < 256) ? rowp[y*256+0] : 0.f;
        v.y = (rk && xg+1 < 256) ? rowp[y*256+1] : 0.f;
        v.z = (rk && xg+2 < 256) ? rowp[y*256+2] : 0.f;
        v.w = (rk && xg+3 < 256) ? rowp[y*256+3] : 0.f;
        *(float4*)(sdst + y*16) = v;
      }
    }
  }
  __syncthreads();

  const f32x4 zero = {0.f, 0.f, 0.f, 0.f};
  #define XFL(nt, ks, dst) { \
    const int px_ = 16*(nt) + l15; \
    const int y_ = (px_*745) >> 13; \
    const float* pp_ = sX + (32*(ks) + 8*h)*192 + y_*16 + (px_ - y_*11) + ox3; \
    union { uint4 u; short8 s; } r_; \
    r_.u.x = pkbf(pp_[0],    pp_[192]); \
    r_.u.y = pkbf(pp_[384],  pp_[576]); \
    r_.u.z = pkbf(pp_[768],  pp_[960]); \
    r_.u.w = pkbf(pp_[1152], pp_[1344]); \
    dst = r_.s; }

  if (!isQ){
    short8 wkf[4][2], wvf[4][2];
    #pragma unroll
    for (int t = 0; t < 4; ++t){
      wkf[t][0] = ldWfrag(Wk, t, 0, l15, h, 1.f);  wkf[t][1] = ldWfrag(Wk, t, 1, l15, h, 1.f);
      wvf[t][0] = ldWfrag(Wv, t, 0, l15, h, 1.f);  wvf[t][1] = ldWfrag(Wv, t, 1, l15, h, 1.f);
    }
    ushort_t* kb = kpkt + (size_t)id*8192;
    ushort_t* vb = vpkt + (size_t)id*8192;
    const int nt0 = 2*wv, nt1 = 2*wv + 1;
    short8 xf0[2], xf1[2];
    XFL(nt0, 0, xf0[0]); XFL(nt0, 1, xf0[1]);
    XFL(nt1, 0, xf1[0]); XFL(nt1, 1, xf1[1]);
    #pragma unroll
    for (int t = 0; t < 4; ++t){
      f32x4 ak0 = MFMA16(wkf[t][0], xf0[0], zero); ak0 = MFMA16(wkf[t][1], xf0[1], ak0);
      f32x4 ak1 = MFMA16(wkf[t][0], xf1[0], zero); ak1 = MFMA16(wkf[t][1], xf1[1], ak1);
      f32x4 av0 = MFMA16(xf0[0], wvf[t][0], zero); av0 = MFMA16(xf0[1], wvf[t][1], av0);
      f32x4 av1 = MFMA16(xf1[0], wvf[t][0], zero); av1 = MFMA16(xf1[1], wvf[t][1], av1);
      storeK8(kb, nt0, t, l15, h, ak0);
      storeK8(kb, nt1, t, l15, h, ak1);
      uint4 pv;
      pv.x = pkbf(av0[0], av0[1]); pv.y = pkbf(av0[2], av0[3]);
      pv.z = pkbf(av1[0], av1[1]); pv.w = pkbf(av1[2], av1[3]);
      *(uint4*)((char*)vb + (size_t)((wv*4 + t)*64 + lane)*16) = pv;
    }
  } else {
    const float C1 = 0.18033688011112042f;   // (1/8)/ln2 folded into Q
    short8 wqf[4][2];
    #pragma unroll
    for (int t = 0; t < 4; ++t){
      wqf[t][0] = ldWfrag(Wq, t, 0, l15, h, C1);  wqf[t][1] = ldWfrag(Wq, t, 1, l15, h, C1);
    }
    ushort_t* qb = qpkt + (size_t)id*8192;
    #pragma unroll
    for (int nn = 0; nn < 2; ++nn){
      const int nt = 2*wv + nn;
      short8 xf[2];
      XFL(nt, 0, xf[0]); XFL(nt, 1, xf[1]);
      #pragma unroll
      for (int t = 0; t < 4; ++t){
        f32x4 aq = MFMA16(wqf[t][0], xf[0], zero); aq = MFMA16(wqf[t][1], xf[1], aq);
        storeK8(qb, nt, t, l15, h, aq);
      }
    }
  }
  #undef XFL
}

// ---------------------------------------------------------------------------
// Kernel 2: attention, S^T form, LDS-pipelined. 128 thr = 2 waves = 1 window.
// Units = (tile, half): 8KB K-half + 8KB V-half. Double buffer 2x16KB.
// wave0 stages K (8x global_load_lds dwordx4), wave1 stages V.
// s_waitcnt vmcnt(8) + s_barrier -> next unit stays in flight during compute.
// ---------------------------------------------------------------------------
__global__ __launch_bounds__(128) void attn_kernel(
    ushort_t* qpkt,                      // aliases rbuf! no __restrict__
    const ushort_t* __restrict__ kpkt, const ushort_t* __restrict__ vpkt,
    const float* __restrict__ gamma)
{
  __shared__ __align__(16) char smem[32768];
  const int tid = threadIdx.x;
  const int lane = tid & 63, wave = tid >> 6;
  const int win = (blockIdx.x & 7)*144 + (blockIdx.x >> 3);   // XCD swizzle
  const int b = win / 576, wid = win % 576, wy = wid / 24, wx = wid % 24;
  const int l15 = lane & 15, h = lane >> 4;

  // resident Q A-frags (this wave's 64-query half)
  short8 qf[4][2];
  {
    const ushort_t* qblk = qpkt + (size_t)win*8192;
    #pragma unroll
    for (int mt = 0; mt < 4; ++mt){
      qf[mt][0] = *(const short8*)(qblk + (size_t)(((4*wave+mt)*2 + 0)*64 + lane)*8);
      qf[mt][1] = *(const short8*)(qblk + (size_t)(((4*wave+mt)*2 + 1)*64 + lane)*8);
    }
  }

  // valid-tile nibble list (uniform; no private arrays -> no scratch)
  uint64 cks = 0; int nv = 0;
  #pragma unroll
  for (int ck = 0; ck < 9; ++ck){
    const int ty = wy - 1 + ck/3, tx = wx - 1 + ck%3;
    if ((unsigned)ty < 24u && (unsigned)tx < 24u){
      cks |= ((uint64)ck) << (4*nv); ++nv;
    }
  }
  const int nu = 2*nv;   // units (tile halves); nv>=4 so nu>=8

  f32x4 o[4][4];
  float lsum[4] = {0.f, 0.f, 0.f, 0.f};
  #pragma unroll
  for (int mt = 0; mt < 4; ++mt)
    #pragma unroll
    for (int u = 0; u < 4; ++u) o[mt][u] = (f32x4){0.f,0.f,0.f,0.f};
  const f32x4 zz = {0.f,0.f,0.f,0.f};

  const ushort_t* gsrcbase = wave ? vpkt : kpkt;
  const int ldsw = wave ? 8192 : 0;

  // stage unit u into buffer bu: 8 x (1KB) global_load_lds dwordx4
  #define STAGE(u, bu) { \
    const int t_ = (u) >> 1, hf_ = (u) & 1; \
    const int ck_ = (int)((cks >> (4*t_)) & 15); \
    const int cy_ = (ck_*11) >> 5; \
    const int ty_ = wy - 1 + cy_, tx_ = wx - 1 + (ck_ - 3*cy_); \
    const char* g_ = (const char*)(gsrcbase + (size_t)(b*576 + ty_*24 + tx_)*8192) \
                     + hf_*8192 + lane*16; \
    char* l_ = smem + (bu)*16384 + ldsw; \
    _Pragma("unroll") \
    for (int i_ = 0; i_ < 8; ++i_) \
      __builtin_amdgcn_global_load_lds( \
        (const __attribute__((address_space(1))) uint32*)(g_ + i_*1024), \
        (__attribute__((address_space(3))) uint32*)(l_ + i_*1024), 16, 0, 0); \
  }

  STAGE(0, 0);
  STAGE(1, 1);

  #pragma unroll 1
  for (int u = 0; u < nu; ++u){
    const int bu = u & 1;
    if (u + 1 < nu) { __asm__ volatile("s_waitcnt vmcnt(8)" ::: "memory"); }
    else            { __asm__ volatile("s_waitcnt vmcnt(0)" ::: "memory"); }
    __builtin_amdgcn_s_barrier();
    __asm__ volatile("" ::: "memory");

    const int t = u >> 1, hf = u & 1;
    const int ckv = (int)((cks >> (4*t)) & 15);
    const int cyv = (ckv*11) >> 5;
    const int tyv = wy - 1 + cyv, txv = wx - 1 + (ckv - 3*cyv);
    const bool ey = (tyv == 23), ex = (txv == 23);
    const char* lk = smem + bu*16384;
    const char* lv = lk + 8192;

    #pragma unroll
    for (int ntpl = 0; ntpl < 2; ++ntpl){
      const int ntp = 2*hf + ntpl;
      short8 kf00 = *(const short8*)(lk + ((4*ntpl+0)*64 + lane)*16);
      short8 kf01 = *(const short8*)(lk + ((4*ntpl+1)*64 + lane)*16);
      short8 kf10 = *(const short8*)(lk + ((4*ntpl+2)*64 + lane)*16);
      short8 kf11 = *(const short8*)(lk + ((4*ntpl+3)*64 + lane)*16);
      short8 vf0  = *(const short8*)(lv + ((4*ntpl+0)*64 + lane)*16);
      short8 vf1  = *(const short8*)(lv + ((4*ntpl+1)*64 + lane)*16);
      short8 vf2  = *(const short8*)(lv + ((4*ntpl+2)*64 + lane)*16);
      short8 vf3  = *(const short8*)(lv + ((4*ntpl+3)*64 + lane)*16);

      bool okk[8];
      #pragma unroll
      for (int kt = 0; kt < 2; ++kt)
        #pragma unroll
        for (int r = 0; r < 4; ++r){
          const int kl = 32*ntp + 16*kt + 4*h + r;
          bool ok = kl < 121;
          if (ey | ex){
            const int ky = (kl*745) >> 13, kx = kl - ky*11;
            if (ey) ok = ok && (ky < 3);
            if (ex) ok = ok && (kx < 3);
          }
          okk[4*kt + r] = ok;
        }

      #pragma unroll
      for (int mt = 0; mt < 4; ++mt){
        f32x4 s0 = MFMA16(kf00, qf[mt][0], zz); s0 = MFMA16(kf01, qf[mt][1], s0);
        f32x4 s1 = MFMA16(kf10, qf[mt][0], zz); s1 = MFMA16(kf11, qf[mt][1], s1);
        float p[8];
        #pragma unroll
        for (int r = 0; r < 4; ++r){
          p[r]   = okk[r]   ? EXP2(s0[r]) : 0.f;   // Q pre-scaled; no running max
          p[4+r] = okk[4+r] ? EXP2(s1[r]) : 0.f;
        }
        lsum[mt] += ((p[0]+p[1]) + (p[2]+p[3])) + ((p[4]+p[5]) + (p[6]+p[7]));
        union { uint4 uu; short8 s; } af;
        af.uu.x = pkbf(p[0], p[1]); af.uu.y = pkbf(p[2], p[3]);
        af.uu.z = pkbf(p[4], p[5]); af.uu.w = pkbf(p[6], p[7]);
        o[mt][0] = MFMA16(af.s, vf0, o[mt][0]);
        o[mt][1] = MFMA16(af.s, vf1, o[mt][1]);
        o[mt][2] = MFMA16(af.s, vf2, o[mt][2]);
        o[mt][3] = MFMA16(af.s, vf3, o[mt][3]);
      }
    }

    __asm__ volatile("" ::: "memory");
    __builtin_amdgcn_s_barrier();        // both waves done with buffer bu
    if (u + 2 < nu) STAGE(u + 2, bu);    // refill it
  }
  #undef STAGE

  // epilogue: lsum[mt] is per-lane partial for query (16mt + l15); reduce over
  // h-groups, fetch per-(h,r) denominator by shuffle, store normalized bf16 r.
  const float gm = gamma[0];
  ushort_t* rb = qpkt + (size_t)win*8192 + (size_t)wave*4096;
  #pragma unroll
  for (int mt = 0; mt < 4; ++mt){
    float v = lsum[mt];
    v += __shfl_xor(v, 16); v += __shfl_xor(v, 32);
    #pragma unroll
    for (int r = 0; r < 4; ++r){
      const float den = __shfl(v, 4*h + r);     // lane with l15' = 4h+r
      const float wg = gm * RCP(den);
      const int qs = 16*mt + 4*h + r;
      #pragma unroll
      for (int u = 0; u < 4; ++u)
        rb[(size_t)qs*64 + 16*u + l15] = f2bf(wg * o[mt][u][r]);
    }
  }
}

// ---------------------------------------------------------------------------
// Kernel 3: out = xref + r. LDS-tiled, both sides coalesced (R4-proven).
// ---------------------------------------------------------------------------
__global__ __launch_bounds__(256) void ep_kernel(
    const float* __restrict__ xref, const ushort_t* __restrict__ rbuf,
    float* __restrict__ out)
{
  __shared__ float tile[64][65];
  const int tid = threadIdx.x;
  const int bidx = blockIdx.x;                 // 2048 = b(2) x y(256) x xc(4)
  const int xc = bidx & 3, y = (bidx >> 2) & 255, b = bidx >> 10;
  const int wy = (y*745) >> 13, qy = y - wy*11;
  {
    const int ch = tid & 63, xs4 = tid >> 6;
    #pragma unroll
    for (int xi = 0; xi < 16; ++xi){
      const int xl = xi*4 + xs4;
      const int x = xc*64 + xl;
      const int wx = (x*745) >> 13, qx = x - wx*11;
      const size_t ridx = (size_t)(b*576 + wy*24 + wx)*8192 + (size_t)(qy*11 + qx)*64 + ch;
      tile[xl][ch] = __uint_as_float(((uint32)rbuf[ridx]) << 16);
    }
  }
  __syncthreads();
  {
    const int xl = tid & 63, cg = tid >> 6;
    const size_t base = (size_t)b*4194304 + (size_t)y*256 + xc*64 + xl;
    #pragma unroll
    for (int ci = 0; ci < 16; ++ci){
      const int c2 = ci*4 + cg;
      const size_t idx = base + (size_t)c2*65536;
      out[idx] = xref[idx] + tile[xl][c2];
    }
  }
}

// ---------------------------------------------------------------------------
extern "C" void kernel_launch(void* const* d_in, const int* in_sizes, int n_in,
                              void* d_out, int out_size, void* d_ws, size_t ws_size,
                              hipStream_t stream)
{
  const float* xk = (const float*)d_in[0];
  const float* xr = (const float*)d_in[1];
  const float* Wq = (const float*)d_in[2];
  const float* Wk = (const float*)d_in[3];
  const float* Wv = (const float*)d_in[4];
  const float* gm = (const float*)d_in[5];
  float* out = (float*)d_out;
  char* ws = (char*)d_ws;
  ushort_t* qp = (ushort_t*)(ws + QPKT_OFF);   // rbuf overlays this region
  ushort_t* kp = (ushort_t*)(ws + KPKT_OFF);
  ushort_t* vp = (ushort_t*)(ws + VPKT_OFF);
  (void)in_sizes; (void)n_in; (void)out_size; (void)ws_size;  // needs 56.6 MiB

  proj_kernel<<<2304, 256, 0, stream>>>(xk, xr, Wq, Wk, Wv, qp, kp, vp);
  attn_kernel<<<1152, 128, 0, stream>>>(qp, kp, vp, gm);
  ep_kernel<<<2048, 256, 0, stream>>>(xr, qp, out);
}

// Round 6
// 236.548 us; speedup vs baseline: 1.8306x; 1.0614x over previous
//
#include <hip/hip_runtime.h>

// ---------------------------------------------------------------------------
// CAPA_62886911148616: windowed local attention, SC=11, c=64, b=2, 256x256.
// R6: attn = 256-thr blocks, wave = (query-half, key-half); validity as
// MFMA-C-init bias (-1e4); softmax denominator via ones-MFMA (C-layout);
// LDS partial-O merge. Staging pipeline (global_load_lds + vmcnt(4)) kept.
// MFMA f32_16x16x32_bf16: A m=lane&15,k=8h+j; B n=lane&15,k=8h+j;
// C/D col=lane&15, row=4h+reg.
// ---------------------------------------------------------------------------

typedef unsigned short ushort_t;
typedef unsigned int   uint32;
typedef unsigned long long uint64;
typedef __attribute__((ext_vector_type(8))) short short8;   // 8 x bf16 bits
typedef __attribute__((ext_vector_type(4))) float f32x4;

#define MFMA16(a,b,c) __builtin_amdgcn_mfma_f32_16x16x32_bf16(a,b,c,0,0,0)

#if __has_builtin(__builtin_amdgcn_exp2f)
#define EXP2(x) __builtin_amdgcn_exp2f(x)
#else
#define EXP2(x) exp2f(x)
#endif
#if __has_builtin(__builtin_amdgcn_rcpf)
#define RCP(x) __builtin_amdgcn_rcpf(x)
#else
#define RCP(x) (1.0f/(x))
#endif

// ws layout (bytes): Q | K | V packets, each 1152 tiles * 16KB = 56.6 MiB.
// rbuf (bf16 [win][q128][ch64]) overlays qpkt (each attn block reads its own
// window's 16KB fully before writing it).
#define QPKT_OFF   0u
#define KPKT_OFF   18874368u
#define VPKT_OFF   37748736u

__device__ __forceinline__ ushort_t f2bf(float f){
  uint32 u = __float_as_uint(f);
  u = (u + 0x7FFFu + ((u >> 16) & 1u)) >> 16;   // RNE
  return (ushort_t)u;
}

__device__ __forceinline__ uint32 pkbf(float a, float b){
#if __has_builtin(__builtin_amdgcn_cvt_pk_bf16_f32)
  typedef __attribute__((ext_vector_type(2))) __bf16 bf2;
  union { bf2 v; uint32 u; } c;
  c.v = __builtin_amdgcn_cvt_pk_bf16_f32(a, b);
  return c.u;
#else
  return (uint32)f2bf(a) | ((uint32)f2bf(b) << 16);
#endif
}

// store one D[ch][pix] C-frag into K/Q packet layout (8 bytes, R2-verified)
__device__ __forceinline__ void storeK8(ushort_t* __restrict__ base, int nt, int t,
                                        int l15, int h, f32x4 a){
  uint32 lo = pkbf(a[0], a[1]);
  uint32 hi = pkbf(a[2], a[3]);
  int lanep = l15 + 16*((2*t + (h>>1)) & 3);
  size_t off = (size_t)((nt*2 + (t>>1))*64 + lanep)*16 + 8*(h&1);
  *(uint2*)((char*)base + off) = make_uint2(lo, hi);
}

__device__ __forceinline__ short8 ldWfrag(const float* __restrict__ W, int t, int ks,
                                          int l15, int h, float scale){
  const float* p = W + (16*t + l15)*64 + 32*ks + 8*h;
  float4 a = *(const float4*)p;
  float4 b = *(const float4*)(p + 4);
  union { uint4 u; short8 s; } x;
  x.u.x = pkbf(a.x*scale, a.y*scale);
  x.u.y = pkbf(a.z*scale, a.w*scale);
  x.u.z = pkbf(b.x*scale, b.y*scale);
  x.u.w = pkbf(b.z*scale, b.w*scale);
  return x.s;
}

// ---------------------------------------------------------------------------
// Kernel 1: projections (R4-proven, unchanged).
// ---------------------------------------------------------------------------
__global__ __launch_bounds__(256) void proj_kernel(
    const float* __restrict__ xk, const float* __restrict__ xr,
    const float* __restrict__ Wq, const float* __restrict__ Wk, const float* __restrict__ Wv,
    ushort_t* __restrict__ qpkt, ushort_t* __restrict__ kpkt, ushort_t* __restrict__ vpkt)
{
  __shared__ __align__(16) float sX[64*192];
  const int tid = threadIdx.x;
  const int lane = tid & 63, wv = tid >> 6;
  const int l15 = lane & 15, h = lane >> 4;
  const int bid = blockIdx.x;
  const bool isQ = bid >= 1152;
  const int id = isQ ? bid - 1152 : bid;
  const int b = id / 576, rem = id % 576, ty = rem / 24, tx = rem % 24;
  const float* xs = (isQ ? xk : xr) + (size_t)b*64*65536;
  const int oy = ty*11, ox = tx*11;
  const int ox3 = ox & 3, xa = ox - ox3;

  #pragma unroll
  for (int i = tid; i < 1024; i += 256) sX[(i>>4)*192 + 176 + (i&15)] = 0.f;

  {
    const int ch = tid >> 2, seg = tid & 3;
    const float* rowp = xs + (size_t)ch*65536 + (size_t)oy*256 + (xa + 4*seg);
    float* sdst = sX + ch*192 + 4*seg;
    if (ty < 23 && tx < 23){
      #pragma unroll
      for (int y = 0; y < 11; ++y)
        *(float4*)(sdst + y*16) = *(const float4*)(rowp + y*256);
    } else {
      const int xg = xa + 4*seg;
      #pragma unroll
      for (int y = 0; y < 11; ++y){
        const bool rk = (oy + y) < 256;
        float4 v;
        v.x = (rk && xg+0 < 256) ? rowp[y*256+0] : 0.f;
        v.y = (rk && xg+1 < 256) ? rowp[y*256+1] : 0.f;
        v.z = (rk && xg+2 < 256) ? rowp[y*256+2] : 0.f;
        v.w = (rk && xg+3 < 256) ? rowp[y*256+3] : 0.f;
        *(float4*)(sdst + y*16) = v;
      }
    }
  }
  __syncthreads();

  const f32x4 zero = {0.f, 0.f, 0.f, 0.f};
  #define XFL(nt, ks, dst) { \
    const int px_ = 16*(nt) + l15; \
    const int y_ = (px_*745) >> 13; \
    const float* pp_ = sX + (32*(ks) + 8*h)*192 + y_*16 + (px_ - y_*11) + ox3; \
    union { uint4 u; short8 s; } r_; \
    r_.u.x = pkbf(pp_[0],    pp_[192]); \
    r_.u.y = pkbf(pp_[384],  pp_[576]); \
    r_.u.z = pkbf(pp_[768],  pp_[960]); \
    r_.u.w = pkbf(pp_[1152], pp_[1344]); \
    dst = r_.s; }

  if (!isQ){
    short8 wkf[4][2], wvf[4][2];
    #pragma unroll
    for (int t = 0; t < 4; ++t){
      wkf[t][0] = ldWfrag(Wk, t, 0, l15, h, 1.f);  wkf[t][1] = ldWfrag(Wk, t, 1, l15, h, 1.f);
      wvf[t][0] = ldWfrag(Wv, t, 0, l15, h, 1.f);  wvf[t][1] = ldWfrag(Wv, t, 1, l15, h, 1.f);
    }
    ushort_t* kb = kpkt + (size_t)id*8192;
    ushort_t* vb = vpkt + (size_t)id*8192;
    const int nt0 = 2*wv, nt1 = 2*wv + 1;
    short8 xf0[2], xf1[2];
    XFL(nt0, 0, xf0[0]); XFL(nt0, 1, xf0[1]);
    XFL(nt1, 0, xf1[0]); XFL(nt1, 1, xf1[1]);
    #pragma unroll
    for (int t = 0; t < 4; ++t){
      f32x4 ak0 = MFMA16(wkf[t][0], xf0[0], zero); ak0 = MFMA16(wkf[t][1], xf0[1], ak0);
      f32x4 ak1 = MFMA16(wkf[t][0], xf1[0], zero); ak1 = MFMA16(wkf[t][1], xf1[1], ak1);
      f32x4 av0 = MFMA16(xf0[0], wvf[t][0], zero); av0 = MFMA16(xf0[1], wvf[t][1], av0);
      f32x4 av1 = MFMA16(xf1[0], wvf[t][0], zero); av1 = MFMA16(xf1[1], wvf[t][1], av1);
      storeK8(kb, nt0, t, l15, h, ak0);
      storeK8(kb, nt1, t, l15, h, ak1);
      uint4 pv;
      pv.x = pkbf(av0[0], av0[1]); pv.y = pkbf(av0[2], av0[3]);
      pv.z = pkbf(av1[0], av1[1]); pv.w = pkbf(av1[2], av1[3]);
      *(uint4*)((char*)vb + (size_t)((wv*4 + t)*64 + lane)*16) = pv;
    }
  } else {
    const float C1 = 0.18033688011112042f;   // (1/8)/ln2 folded into Q
    short8 wqf[4][2];
    #pragma unroll
    for (int t = 0; t < 4; ++t){
      wqf[t][0] = ldWfrag(Wq, t, 0, l15, h, C1);  wqf[t][1] = ldWfrag(Wq, t, 1, l15, h, C1);
    }
    ushort_t* qb = qpkt + (size_t)id*8192;
    #pragma unroll
    for (int nn = 0; nn < 2; ++nn){
      const int nt = 2*wv + nn;
      short8 xf[2];
      XFL(nt, 0, xf[0]); XFL(nt, 1, xf[1]);
      #pragma unroll
      for (int t = 0; t < 4; ++t){
        f32x4 aq = MFMA16(wqf[t][0], xf[0], zero); aq = MFMA16(wqf[t][1], xf[1], aq);
        storeK8(qb, nt, t, l15, h, aq);
      }
    }
  }
  #undef XFL
}

// ---------------------------------------------------------------------------
// Kernel 2: attention. 256 thr = 4 waves = 1 window; wave = (qh, kh).
// Unit = tile-half (8KB K + 8KB V); each wave stages a 4KB quarter and
// computes its kh's 32 keys for its qh's 64 queries. Bias-init masking,
// ones-MFMA denominator, LDS O-merge, epilogue by kh==0 waves.
// ---------------------------------------------------------------------------
__global__ __launch_bounds__(256) void attn_kernel(
    ushort_t* qpkt,                      // aliases rbuf! no __restrict__
    const ushort_t* __restrict__ kpkt, const ushort_t* __restrict__ vpkt,
    const float* __restrict__ gamma)
{
  __shared__ __align__(16) char smem[32768];
  const int tid = threadIdx.x;
  const int lane = tid & 63, wave = tid >> 6;
  const int qh = wave & 1, kh = wave >> 1;
  const int win = (blockIdx.x & 7)*144 + (blockIdx.x >> 3);   // XCD swizzle
  const int b = win / 576, wid = win % 576, wy = wid / 24, wx = wid % 24;
  const int l15 = lane & 15, h = lane >> 4;

  // resident Q A-frags for this wave's query half
  short8 qf[4][2];
  {
    const ushort_t* qblk = qpkt + (size_t)win*8192;
    #pragma unroll
    for (int mt = 0; mt < 4; ++mt){
      qf[mt][0] = *(const short8*)(qblk + (size_t)(((4*qh+mt)*2 + 0)*64 + lane)*8);
      qf[mt][1] = *(const short8*)(qblk + (size_t)(((4*qh+mt)*2 + 1)*64 + lane)*8);
    }
  }

  // valid-tile nibble list
  uint64 cks = 0; int nv = 0;
  #pragma unroll
  for (int ck = 0; ck < 9; ++ck){
    const int ty = wy - 1 + ck/3, tx = wx - 1 + ck%3;
    if ((unsigned)ty < 24u && (unsigned)tx < 24u){
      cks |= ((uint64)ck) << (4*nv); ++nv;
    }
  }
  const int nu = 2*nv;   // units; nv>=4 so nu>=8

  const f32x4 zz = {0.f,0.f,0.f,0.f};
  f32x4 o[4][4], lsumC[4];
  #pragma unroll
  for (int mt = 0; mt < 4; ++mt){
    lsumC[mt] = zz;
    #pragma unroll
    for (int u = 0; u < 4; ++u) o[mt][u] = zz;
  }
  // interior bias for ntp==3,kt==1: key 112+4h+r invalid iff 4h+r>=9
  f32x4 init_i;
  #pragma unroll
  for (int r = 0; r < 4; ++r) init_i[r] = (4*h + r >= 9) ? -1.0e4f : 0.f;
  // ones B-frag for denominator MFMA
  short8 ones;
  #pragma unroll
  for (int j = 0; j < 8; ++j) ones[j] = (short)0x3F80;

  const ushort_t* gsrc = (wave < 2) ? kpkt : vpkt;
  const int ldsoff = (wave >> 1)*8192 + (wave & 1)*4096;

  #define STAGE(u, bu) { \
    const int t_ = (u) >> 1, hf_ = (u) & 1; \
    const int ck_ = (int)((cks >> (4*t_)) & 15); \
    const int cy_ = (ck_*11) >> 5; \
    const int ty_ = wy - 1 + cy_, tx_ = wx - 1 + (ck_ - 3*cy_); \
    const char* g_ = (const char*)(gsrc + (size_t)(b*576 + ty_*24 + tx_)*8192) \
                     + hf_*8192 + (wave & 1)*4096 + lane*16; \
    char* l_ = smem + (bu)*16384 + ldsoff + lane*16; \
    _Pragma("unroll") \
    for (int i_ = 0; i_ < 4; ++i_) \
      __builtin_amdgcn_global_load_lds( \
        (const __attribute__((address_space(1))) uint32*)(g_ + i_*1024), \
        (__attribute__((address_space(3))) uint32*)(l_ + i_*1024), 16, 0, 0); \
  }

  STAGE(0, 0);
  STAGE(1, 1);

  #pragma unroll 1
  for (int u = 0; u < nu; ++u){
    const int bu = u & 1;
    if (u + 1 < nu) { __asm__ volatile("s_waitcnt vmcnt(4)" ::: "memory"); }
    else            { __asm__ volatile("s_waitcnt vmcnt(0)" ::: "memory"); }
    __builtin_amdgcn_s_barrier();
    __asm__ volatile("" ::: "memory");

    const int t = u >> 1, hf = u & 1;
    const int ckv = (int)((cks >> (4*t)) & 15);
    const int cyv = (ckv*11) >> 5;
    const int tyv = wy - 1 + cyv, txv = wx - 1 + (ckv - 3*cyv);
    const bool ey = (tyv == 23), ex = (txv == 23);
    const int ntp = 2*hf + kh;

    // S-MFMA accumulator-init bias (masking); wave-uniform branch
    f32x4 b0, b1;
    if (ey | ex){
      #pragma unroll
      for (int kt = 0; kt < 2; ++kt){
        f32x4 bb;
        #pragma unroll
        for (int r = 0; r < 4; ++r){
          const int kl = 32*ntp + 16*kt + 4*h + r;
          const int ky = (kl*745) >> 13, kx = kl - ky*11;
          bool ok = (kl < 121) && (!ey || ky < 3) && (!ex || kx < 3);
          bb[r] = ok ? 0.f : -1.0e4f;
        }
        if (kt) b1 = bb; else b0 = bb;
      }
    } else {
      b0 = zz;
      b1 = (hf & kh) ? init_i : zz;   // ntp==3, kt==1 pad keys
    }

    const char* lk = smem + bu*16384 + kh*4096;
    const char* lv = smem + bu*16384 + 8192 + kh*4096;
    short8 kf00 = *(const short8*)(lk + (0*64 + lane)*16);
    short8 kf01 = *(const short8*)(lk + (1*64 + lane)*16);
    short8 kf10 = *(const short8*)(lk + (2*64 + lane)*16);
    short8 kf11 = *(const short8*)(lk + (3*64 + lane)*16);
    short8 vf0  = *(const short8*)(lv + (0*64 + lane)*16);
    short8 vf1  = *(const short8*)(lv + (1*64 + lane)*16);
    short8 vf2  = *(const short8*)(lv + (2*64 + lane)*16);
    short8 vf3  = *(const short8*)(lv + (3*64 + lane)*16);

    #pragma unroll
    for (int mt = 0; mt < 4; ++mt){
      f32x4 s0 = MFMA16(kf00, qf[mt][0], b0); s0 = MFMA16(kf01, qf[mt][1], s0);
      f32x4 s1 = MFMA16(kf10, qf[mt][0], b1); s1 = MFMA16(kf11, qf[mt][1], s1);
      float p[8];
      #pragma unroll
      for (int r = 0; r < 4; ++r){
        p[r]   = EXP2(s0[r]);   // Q pre-scaled; invalid keys carry -1e4 bias -> 0
        p[4+r] = EXP2(s1[r]);
      }
      union { uint4 uu; short8 s; } af;
      af.uu.x = pkbf(p[0], p[1]); af.uu.y = pkbf(p[2], p[3]);
      af.uu.z = pkbf(p[4], p[5]); af.uu.w = pkbf(p[6], p[7]);
      o[mt][0] = MFMA16(af.s, vf0, o[mt][0]);
      o[mt][1] = MFMA16(af.s, vf1, o[mt][1]);
      o[mt][2] = MFMA16(af.s, vf2, o[mt][2]);
      o[mt][3] = MFMA16(af.s, vf3, o[mt][3]);
      lsumC[mt] = MFMA16(af.s, ones, lsumC[mt]);   // denominator, C-layout
    }

    __asm__ volatile("" ::: "memory");
    __builtin_amdgcn_s_barrier();        // all 4 waves done with buffer bu
    if (u + 2 < nu) STAGE(u + 2, bu);
  }
  #undef STAGE

  // ---- merge partial O / lsum across key-halves (via LDS) ----
  __syncthreads();
  {
    float* base = (float*)(smem + qh*12288);
    if (kh){
      #pragma unroll
      for (int mt = 0; mt < 4; ++mt){
        *(f32x4*)(base + (mt*2+0)*256 + lane*4) = o[mt][0];
        *(f32x4*)(base + (mt*2+1)*256 + lane*4) = o[mt][1];
        *(f32x4*)(base + (8+mt)*256 + lane*4)   = lsumC[mt];
      }
    }
  }
  __syncthreads();
  if (!kh){
    float* base = (float*)(smem + qh*12288);
    #pragma unroll
    for (int mt = 0; mt < 4; ++mt){
      o[mt][0] += *(const f32x4*)(base + (mt*2+0)*256 + lane*4);
      o[mt][1] += *(const f32x4*)(base + (mt*2+1)*256 + lane*4);
      lsumC[mt] += *(const f32x4*)(base + (8+mt)*256 + lane*4);
    }
  }
  __syncthreads();
  {
    float* base2 = (float*)(smem + qh*8192);
    if (kh){
      #pragma unroll
      for (int mt = 0; mt < 4; ++mt){
        *(f32x4*)(base2 + (mt*2+0)*256 + lane*4) = o[mt][2];
        *(f32x4*)(base2 + (mt*2+1)*256 + lane*4) = o[mt][3];
      }
    }
  }
  __syncthreads();
  if (!kh){
    float* base2 = (float*)(smem + qh*8192);
    #pragma unroll
    for (int mt = 0; mt < 4; ++mt){
      o[mt][2] += *(const f32x4*)(base2 + (mt*2+0)*256 + lane*4);
      o[mt][3] += *(const f32x4*)(base2 + (mt*2+1)*256 + lane*4);
    }
    // ---- epilogue: normalize + store bf16 r into this window's qpkt ----
    const float gm = gamma[0];
    ushort_t* rb = qpkt + (size_t)win*8192 + (size_t)qh*4096;
    #pragma unroll
    for (int mt = 0; mt < 4; ++mt){
      #pragma unroll
      for (int r = 0; r < 4; ++r){
        const float wg = gm * RCP(lsumC[mt][r]);   // den already per-lane (C-layout)
        const int qs = 16*mt + 4*h + r;
        #pragma unroll
        for (int u = 0; u < 4; ++u)
          rb[(size_t)qs*64 + 16*u + l15] = f2bf(wg * o[mt][u][r]);
      }
    }
  }
}

// ---------------------------------------------------------------------------
// Kernel 3: out = xref + r. LDS-tiled, both sides coalesced (R4-proven).
// ---------------------------------------------------------------------------
__global__ __launch_bounds__(256) void ep_kernel(
    const float* __restrict__ xref, const ushort_t* __restrict__ rbuf,
    float* __restrict__ out)
{
  __shared__ float tile[64][65];
  const int tid = threadIdx.x;
  const int bidx = blockIdx.x;                 // 2048 = b(2) x y(256) x xc(4)
  const int xc = bidx & 3, y = (bidx >> 2) & 255, b = bidx >> 10;
  const int wy = (y*745) >> 13, qy = y - wy*11;
  {
    const int ch = tid & 63, xs4 = tid >> 6;
    #pragma unroll
    for (int xi = 0; xi < 16; ++xi){
      const int xl = xi*4 + xs4;
      const int x = xc*64 + xl;
      const int wx = (x*745) >> 13, qx = x - wx*11;
      const size_t ridx = (size_t)(b*576 + wy*24 + wx)*8192 + (size_t)(qy*11 + qx)*64 + ch;
      tile[xl][ch] = __uint_as_float(((uint32)rbuf[ridx]) << 16);
    }
  }
  __syncthreads();
  {
    const int xl = tid & 63, cg = tid >> 6;
    const size_t base = (size_t)b*4194304 + (size_t)y*256 + xc*64 + xl;
    #pragma unroll
    for (int ci = 0; ci < 16; ++ci){
      const int c2 = ci*4 + cg;
      const size_t idx = base + (size_t)c2*65536;
      out[idx] = xref[idx] + tile[xl][c2];
    }
  }
}

// ---------------------------------------------------------------------------
extern "C" void kernel_launch(void* const* d_in, const int* in_sizes, int n_in,
                              void* d_out, int out_size, void* d_ws, size_t ws_size,
                              hipStream_t stream)
{
  const float* xk = (const float*)d_in[0];
  const float* xr = (const float*)d_in[1];
  const float* Wq = (const float*)d_in[2];
  const float* Wk = (const float*)d_in[3];
  const float* Wv = (const float*)d_in[4];
  const float* gm = (const float*)d_in[5];
  float* out = (float*)d_out;
  char* ws = (char*)d_ws;
  ushort_t* qp = (ushort_t*)(ws + QPKT_OFF);   // rbuf overlays this region
  ushort_t* kp = (ushort_t*)(ws + KPKT_OFF);
  ushort_t* vp = (ushort_t*)(ws + VPKT_OFF);
  (void)in_sizes; (void)n_in; (void)out_size; (void)ws_size;  // needs 56.6 MiB

  proj_kernel<<<2304, 256, 0, stream>>>(xk, xr, Wq, Wk, Wv, qp, kp, vp);
  attn_kernel<<<1152, 256, 0, stream>>>(qp, kp, vp, gm);
  ep_kernel<<<2048, 256, 0, stream>>>(xr, qp, out);
}